// Round 1
// baseline (1004.432 us; speedup 1.0000x reference)
//
#include <hip/hip_runtime.h>
#include <math.h>

// Problem constants (from reference)
#define N_NODES   100000
#define N_EDGES   1600000
#define NUM_RBF   128
#define NUM_GAUSS 32
#define NFEAT     160      // 128 + 32 -> 40 float4 columns per edge
#define CUTOFF    6.0f

#define EPB    64          // edges per block
#define BLOCK  320         // 5 waves; 320/40 = 8 edges processed per iteration
#define COLS   40          // float4 columns per edge
#define EPI    (BLOCK/COLS) // 8 edges per iteration
#define NITER  (EPB/EPI)    // 8 iterations

// Raw clang ext vector so __builtin_nontemporal_store accepts it
typedef float vf4 __attribute__((ext_vector_type(4)));

static __device__ __forceinline__ float fast_exp2(float x) {
#if __has_builtin(__builtin_amdgcn_exp2f)
    return __builtin_amdgcn_exp2f(x);   // raw v_exp_f32 (D = 2^S0)
#else
    return __expf(0.6931471805599453f * x);
#endif
}

__global__ __launch_bounds__(BLOCK) void edge_feat_kernel(
    const float* __restrict__ pos,     // [N_NODES, 3]
    const int*   __restrict__ eidx,    // [2, N_EDGES]
    float*       __restrict__ out)     // [N_EDGES, 160]
{
    __shared__ float4 s_edge[EPB];     // (dist, cutoff, exp(-alpha*d), 0)

    const int blockEdge0 = blockIdx.x * EPB;
    const int tid = threadIdx.x;

    // ---- Phase 1: per-edge scalars (threads 0..63) ----
    if (tid < EPB) {
        const int e = blockEdge0 + tid;
        const int s = eidx[e];
        const int t = eidx[N_EDGES + e];
        const float dx = pos[3*s + 0] - pos[3*t + 0];
        const float dy = pos[3*s + 1] - pos[3*t + 1];
        const float dz = pos[3*s + 2] - pos[3*t + 2];
        const float dist = sqrtf(dx*dx + dy*dy + dz*dz + 1e-12f);
        const float c = 0.5f * (__cosf(dist * (float)(M_PI / 6.0)) + 1.0f);
        const float cc = (dist < CUTOFF) ? c : 0.0f;
        const float te = __expf(-(5.0f / 6.0f) * dist);
        s_edge[tid] = make_float4(dist, cc, te, 0.0f);
    }
    __syncthreads();

    // ---- Per-thread loop-invariant constants (fixed feature column) ----
    const int col   = tid % COLS;       // float4 column 0..39
    const int eiter = tid / COLS;       // edge slot within an iteration 0..7
    const bool isRBF = (col < NUM_RBF / 4);

    // Reference constants (double-folded)
    const float start = (float)0.0024787521766663585;            // exp(-6)
    const float mstep = (float)((1.0 - 0.0024787521766663585) / (NUM_RBF - 1));
    const float beta  = (float)(1.0 /
        ((2.0 / NUM_RBF * (1.0 - 0.0024787521766663585)) *
         (2.0 / NUM_RBF * (1.0 - 0.0024787521766663585))));      // ~4116.4
    const float gstep = (float)(10.0 / (NUM_GAUSS - 1));
    const float ginv  = 20.48f;                                   // 1/(2*w^2)
    const float LOG2E = 1.4426950408889634f;

    // Centers for this thread's 4 features + sqrt(B*log2e) scale
    const int f0 = col * 4;
    float4 C;
    float SB;
    if (isRBF) {
        C.x = start + (float)(f0 + 0) * mstep;
        C.y = start + (float)(f0 + 1) * mstep;
        C.z = start + (float)(f0 + 2) * mstep;
        C.w = start + (float)(f0 + 3) * mstep;
        SB  = sqrtf(beta * LOG2E);
    } else {
        const int g0 = f0 - NUM_RBF;
        C.x = (float)(g0 + 0) * gstep;
        C.y = (float)(g0 + 1) * gstep;
        C.z = (float)(g0 + 2) * gstep;
        C.w = (float)(g0 + 3) * gstep;
        SB  = sqrtf(ginv * LOG2E);
    }

    // ---- Phase 2: iterate over edges; stores contiguous across the block ----
    // Output is write-once, never re-read: use nontemporal stores so the
    // 1.02 GB stream does not write-allocate in L2/LLC (pure HBM write path).
    vf4* out4 = (vf4*)(out + (size_t)blockEdge0 * NFEAT);
    #pragma unroll
    for (int k = 0; k < NITER; ++k) {
        const float4 es = s_edge[k * EPI + eiter];  // broadcast read
        const float X = isRBF ? es.z : es.x;        // exp(-alpha*d) or d
        const float A = isRBF ? es.y : 1.0f;        // cutoff or 1
        vf4 r;
        {
            const float vx = (X - C.x) * SB;
            const float vy = (X - C.y) * SB;
            const float vz = (X - C.z) * SB;
            const float vw = (X - C.w) * SB;
            r.x = A * fast_exp2(-vx * vx);
            r.y = A * fast_exp2(-vy * vy);
            r.z = A * fast_exp2(-vz * vz);
            r.w = A * fast_exp2(-vw * vw);
        }
        __builtin_nontemporal_store(r, out4 + k * BLOCK + tid);
    }
}

extern "C" void kernel_launch(void* const* d_in, const int* in_sizes, int n_in,
                              void* d_out, int out_size, void* d_ws, size_t ws_size,
                              hipStream_t stream) {
    const float* pos  = (const float*)d_in[0];
    const int*   eidx = (const int*)d_in[1];
    float*       out  = (float*)d_out;

    const int nblocks = N_EDGES / EPB;   // 25,000
    edge_feat_kernel<<<nblocks, BLOCK, 0, stream>>>(pos, eidx, out);
}